// Round 8
// baseline (369.388 us; speedup 1.0000x reference)
//
#include <hip/hip_runtime.h>
#include <hip/hip_bf16.h>

typedef __attribute__((ext_vector_type(8))) _Float16 f16x8;
typedef __attribute__((ext_vector_type(2))) __fp16 fp16x2;
typedef __attribute__((ext_vector_type(4))) float f32x4;
typedef unsigned short u16;
typedef unsigned int u32;

#define S_LEN 2048
#define NH    16
#define DK    64
#define DMODEL 1024
#define GSTR  72   // LDS row stride (f16 elems) for BK=64 GEMM tiles

union F16U { _Float16 h; u16 u; };
__device__ __forceinline__ u16 f2h(float f) {
    F16U v; v.h = (_Float16)f; return v.u;
}
union PKU { fp16x2 h; u32 u; };
__device__ __forceinline__ u32 pkrtz(float a, float b) {
    PKU v; v.h = __builtin_amdgcn_cvt_pkrtz(a, b); return v.u;
}

// ------------------------- fused prep kernel -------------------------------
// blk [0,2048): x -> fp16. blk [2048,3072): W^T fp16 [n][k]. blk [3072,3328): bias table.
__global__ __launch_bounds__(256) void prep_kernel(
    const float* __restrict__ x,
    const float* __restrict__ Wq, const float* __restrict__ Wk,
    const float* __restrict__ Wv, const float* __restrict__ Wo,
    const float* __restrict__ rel_emb,
    u16* __restrict__ Xf, u16* __restrict__ WT, float* __restrict__ tab)
{
    __shared__ __align__(16) float T[64 * 68];
    const int blk = blockIdx.x;
    const int tid = threadIdx.x;

    if (blk < 2048) {
        long i8 = ((long)blk * 256 + tid) * 8;
        float4 a = *(const float4*)&x[i8];
        float4 b = *(const float4*)&x[i8 + 4];
        *(ushort4*)&Xf[i8] =
            make_ushort4(f2h(a.x), f2h(a.y), f2h(a.z), f2h(a.w));
        *(ushort4*)&Xf[i8 + 4] =
            make_ushort4(f2h(b.x), f2h(b.y), f2h(b.z), f2h(b.w));
    } else if (blk < 3072) {
        int id = blk - 2048;
        int z = id >> 8, rem = id & 255;
        int k0 = (rem >> 4) * 64, n0 = (rem & 15) * 64;
        const float* src = (z == 0) ? Wq : (z == 1) ? Wk : (z == 2) ? Wv : Wo;
        u16* dT = WT + (long)z * 1048576;
        #pragma unroll
        for (int u = 0; u < 4; u++) {
            int w = tid + u * 256;
            int r = w >> 4, c4 = (w & 15) * 4;
            *(float4*)&T[r * 68 + c4] =
                *(const float4*)&src[(long)(k0 + r) * DMODEL + n0 + c4];
        }
        __syncthreads();
        #pragma unroll
        for (int u = 0; u < 4; u++) {
            int w = tid + u * 256;
            int n = w >> 4, kc = (w & 15) * 4;
            *(ushort4*)&dT[(long)(n0 + n) * DMODEL + k0 + kc] = make_ushort4(
                f2h(T[(kc + 0) * 68 + n]), f2h(T[(kc + 1) * 68 + n]),
                f2h(T[(kc + 2) * 68 + n]), f2h(T[(kc + 3) * 68 + n]));
        }
    } else {
        // bias table: integer-exact replica of reference fp32 bucket math
        int idx = (blk - 3072) * 256 + tid;   // 0..65535
        int h = idx >> 12;
        int t = idx & 4095;
        int n = -(t - 2048);       // q - k
        int ret = 0;
        if (n < 0) { ret = 16; n = -n; }
        int inner;
        if (n < 8) {
            inner = n;
        } else {
            inner = 8 + (n >= 12) + (n >= 16) + (n >= 23) + (n >= 32)
                      + (n >= 46) + (n >= 64) + (n >= 91);
            if (inner > 15) inner = 15;
        }
        tab[h * 4096 + t] = rel_emb[(ret + inner) * NH + h];
    }
}

// ------------------------- pipelined MFMA GEMM (fp16) ----------------------
// C[4096,1024] = A[4096,1024] @ W^T-plane; row-major ushort4 epilogue (C^T
// operand swap). BK=64, register-prefetch staging: global loads for tile k+1
// issue right after the barrier and land during tile-k compute.
__global__ __launch_bounds__(256, 3) void gemm_qkv_mfma(
    const u16* __restrict__ Xf, const u16* __restrict__ WT,
    u16* __restrict__ Qc, u16* __restrict__ Kc, u16* __restrict__ Vc)
{
    const int z = blockIdx.z;
    const u16* BT = WT + (long)z * 1048576;
    u16* O = (z == 0) ? Qc : (z == 1) ? Kc : Vc;

    __shared__ __align__(16) u16 Ah[128 * GSTR], Bh[128 * GSTR];

    const int tid = threadIdx.x;
    const int wv = tid >> 6, lane = tid & 63;
    const int g = lane >> 4, li = lane & 15;
    const int wr = wv >> 1, wc = wv & 1;
    const int bm = blockIdx.y * 128, bn = blockIdx.x * 128;

    const int srow = tid >> 3, sc8 = (tid & 7) * 8;   // staging map (u stride 32 rows)

    f32x4 acc[4][4];
    #pragma unroll
    for (int i = 0; i < 4; i++)
        #pragma unroll
        for (int j = 0; j < 4; j++) acc[i][j] = (f32x4){0.f, 0.f, 0.f, 0.f};

    uint4 ra[4], rb[4];
    #pragma unroll
    for (int u = 0; u < 4; u++) {
        ra[u] = *(const uint4*)&Xf[(long)(bm + srow + u * 32) * DMODEL + sc8];
        rb[u] = *(const uint4*)&BT[(long)(bn + srow + u * 32) * DMODEL + sc8];
    }

    for (int k0 = 0; k0 < DMODEL; k0 += 64) {
        // commit staged regs
        #pragma unroll
        for (int u = 0; u < 4; u++) {
            *(uint4*)&Ah[(srow + u * 32) * GSTR + sc8] = ra[u];
            *(uint4*)&Bh[(srow + u * 32) * GSTR + sc8] = rb[u];
        }
        __syncthreads();

        int nk = k0 + 64;
        if (nk < DMODEL) {
            #pragma unroll
            for (int u = 0; u < 4; u++) {
                ra[u] = *(const uint4*)&Xf[(long)(bm + srow + u * 32) * DMODEL + nk + sc8];
                rb[u] = *(const uint4*)&BT[(long)(bn + srow + u * 32) * DMODEL + nk + sc8];
            }
        }

        #pragma unroll
        for (int kk = 0; kk < 2; kk++) {
            f16x8 a_h[4], b_h[4];
            #pragma unroll
            for (int i = 0; i < 4; i++)
                a_h[i] = *(const f16x8*)&Ah[(wr * 64 + i * 16 + li) * GSTR + kk * 32 + g * 8];
            #pragma unroll
            for (int j = 0; j < 4; j++)
                b_h[j] = *(const f16x8*)&Bh[(wc * 64 + j * 16 + li) * GSTR + kk * 32 + g * 8];
            #pragma unroll
            for (int i = 0; i < 4; i++)
                #pragma unroll
                for (int j = 0; j < 4; j++)
                    acc[i][j] = __builtin_amdgcn_mfma_f32_16x16x32_f16(
                        b_h[j], a_h[i], acc[i][j], 0, 0, 0);   // C^T
        }
        __syncthreads();
    }

    // row-major epilogue: lane holds 4 consecutive n-cols at s-row = li
    #pragma unroll
    for (int i = 0; i < 4; i++) {
        int srw = bm + wr * 64 + i * 16 + li;
        #pragma unroll
        for (int j = 0; j < 4; j++) {
            int ncol = bn + wc * 64 + j * 16 + g * 4;
            *(ushort4*)&O[(long)srw * DMODEL + ncol] = make_ushort4(
                f2h(acc[i][j][0]), f2h(acc[i][j][1]),
                f2h(acc[i][j][2]), f2h(acc[i][j][3]));
        }
    }
}

// ------------------------- pipelined output GEMM (fp16 -> fp32) ------------
__global__ __launch_bounds__(256, 3) void gemm_out_mfma(
    const u16* __restrict__ Ab, const u16* __restrict__ WT,
    float* __restrict__ O)
{
    const u16* BT = WT + 3L * 1048576;
    __shared__ __align__(16) u16 Ah[128 * GSTR], Bh[128 * GSTR];

    const int tid = threadIdx.x;
    const int wv = tid >> 6, lane = tid & 63;
    const int g = lane >> 4, li = lane & 15;
    const int wr = wv >> 1, wc = wv & 1;
    const int bm = blockIdx.y * 128, bn = blockIdx.x * 128;
    const int srow = tid >> 3, sc8 = (tid & 7) * 8;

    f32x4 acc[4][4];
    #pragma unroll
    for (int i = 0; i < 4; i++)
        #pragma unroll
        for (int j = 0; j < 4; j++) acc[i][j] = (f32x4){0.f, 0.f, 0.f, 0.f};

    uint4 ra[4], rb[4];
    #pragma unroll
    for (int u = 0; u < 4; u++) {
        ra[u] = *(const uint4*)&Ab[(long)(bm + srow + u * 32) * DMODEL + sc8];
        rb[u] = *(const uint4*)&BT[(long)(bn + srow + u * 32) * DMODEL + sc8];
    }

    for (int k0 = 0; k0 < DMODEL; k0 += 64) {
        #pragma unroll
        for (int u = 0; u < 4; u++) {
            *(uint4*)&Ah[(srow + u * 32) * GSTR + sc8] = ra[u];
            *(uint4*)&Bh[(srow + u * 32) * GSTR + sc8] = rb[u];
        }
        __syncthreads();

        int nk = k0 + 64;
        if (nk < DMODEL) {
            #pragma unroll
            for (int u = 0; u < 4; u++) {
                ra[u] = *(const uint4*)&Ab[(long)(bm + srow + u * 32) * DMODEL + nk + sc8];
                rb[u] = *(const uint4*)&BT[(long)(bn + srow + u * 32) * DMODEL + nk + sc8];
            }
        }

        #pragma unroll
        for (int kk = 0; kk < 2; kk++) {
            f16x8 a_h[4], b_h[4];
            #pragma unroll
            for (int i = 0; i < 4; i++)
                a_h[i] = *(const f16x8*)&Ah[(wr * 64 + i * 16 + li) * GSTR + kk * 32 + g * 8];
            #pragma unroll
            for (int j = 0; j < 4; j++)
                b_h[j] = *(const f16x8*)&Bh[(wc * 64 + j * 16 + li) * GSTR + kk * 32 + g * 8];
            #pragma unroll
            for (int i = 0; i < 4; i++)
                #pragma unroll
                for (int j = 0; j < 4; j++)
                    acc[i][j] = __builtin_amdgcn_mfma_f32_16x16x32_f16(
                        b_h[j], a_h[i], acc[i][j], 0, 0, 0);   // C^T
        }
        __syncthreads();
    }

    #pragma unroll
    for (int i = 0; i < 4; i++) {
        int grow = bm + wr * 64 + i * 16 + li;
        #pragma unroll
        for (int j = 0; j < 4; j++) {
            int gcol = bn + wc * 64 + j * 16 + g * 4;
            *(float4*)&O[(long)grow * DMODEL + gcol] = make_float4(
                acc[i][j][0], acc[i][j][1], acc[i][j][2], acc[i][j][3]);
        }
    }
}

// ------------- V transpose: row-major [B*S, H*64] -> VT [B,H,Dk,S] ---------
__global__ __launch_bounds__(256) void transpose_v(
    const u16* __restrict__ Vc, u16* __restrict__ VT)
{
    __shared__ __align__(16) u16 t[64 * 72];
    const int blk = blockIdx.x;           // 1024 = 32 s-tiles x 32 bh
    const int st = blk & 31, bh = blk >> 5;
    const int b = bh >> 4, h = bh & 15;
    const int s0 = st * 64;
    const u16* src = Vc + ((long)b * S_LEN + s0) * DMODEL + h * DK;
    u16* dst = VT + (long)bh * DK * S_LEN;
    const int tid = threadIdx.x;

    #pragma unroll
    for (int u = 0; u < 2; u++) {
        int w = tid + u * 256;
        int s = w >> 3, c8 = (w & 7) * 8;
        *(uint4*)&t[s * 72 + c8] = *(const uint4*)&src[(long)s * DMODEL + c8];
    }
    __syncthreads();
    #pragma unroll
    for (int u = 0; u < 2; u++) {
        int w = tid + u * 256;
        int d = w >> 3, sc8 = (w & 7) * 8;
        u16 tmp[8];
        #pragma unroll
        for (int j = 0; j < 8; j++) tmp[j] = t[(sc8 + j) * 72 + d];
        *(ushort4*)&dst[(long)d * S_LEN + s0 + sc8]     = make_ushort4(tmp[0], tmp[1], tmp[2], tmp[3]);
        *(ushort4*)&dst[(long)d * S_LEN + s0 + sc8 + 4] = make_ushort4(tmp[4], tmp[5], tmp[6], tmp[7]);
    }
}

// ------------------------- MFMA flash attention (fp16, S^T softmax) --------
// S^T = K·Q^T: each lane owns ONE query (col=li), 16 keys in regs.
// Q/K read from row-major [B*S, H*64]; V^T from [B,H,Dk,S].
#define APAD 72
#define BIAS_LEN 2112

__global__ __launch_bounds__(256, 4) void attn_mfma(
    const u16* __restrict__ Qf, const u16* __restrict__ Kf,
    const u16* __restrict__ VT, const float* __restrict__ tab,
    u16* __restrict__ ctxb)
{
    __shared__ __align__(16) u16 Ks[64 * APAD];
    __shared__ __align__(16) u16 Vs[64 * APAD];    // [dim][key]
    __shared__ __align__(16) u16 Ps[64 * APAD];    // [q][key], wave-private rows
    __shared__ float biasL[BIAS_LEN];

    const int tid = threadIdx.x;
    const int wv = tid >> 6, lane = tid & 63;
    const int g = lane >> 4, li = lane & 15;
    const int qblk = blockIdx.x & 31;
    const int h = (blockIdx.x >> 5) & 15;
    const int b = blockIdx.x >> 9;
    const int q0 = qblk * 64;
    const long bh = b * NH + h;
    const int qloc = wv * 16 + li;     // this lane's query (within block)

    const u16* KhG = Kf + (long)b * S_LEN * DMODEL + h * DK;   // row stride DMODEL
    const u16* VtG = VT + bh * (DK * S_LEN);
    const float* th = tab + h * 4096;

    {
        const float* tb = th + 2048 - q0 - 63;
        for (int j = tid; j < BIAS_LEN; j += 256) biasL[j] = tb[j];
    }

    f16x8 q0f, q1f;
    {
        const u16* ph = Qf + ((long)b * S_LEN + q0 + qloc) * DMODEL + h * DK + g * 8;
        q0f = *(const f16x8*)ph;  q1f = *(const f16x8*)(ph + 32);
    }

    f32x4 Oc[4];
    #pragma unroll
    for (int n = 0; n < 4; n++) Oc[n] = (f32x4){0.f, 0.f, 0.f, 0.f};
    float mP = -1e30f, lR = 0.f;

    // staging register prefetch (2 rows of K and V per thread)
    const int srow = tid >> 3, sc8 = (tid & 7) * 8;        // u=0
    const int srow1 = srow + 32;                           // u=1
    uint4 kreg0, kreg1, vreg0, vreg1;
    kreg0 = *(const uint4*)&KhG[(long)srow * DMODEL + sc8];
    kreg1 = *(const uint4*)&KhG[(long)srow1 * DMODEL + sc8];
    vreg0 = *(const uint4*)&VtG[(long)srow * S_LEN + sc8];
    vreg1 = *(const uint4*)&VtG[(long)srow1 * S_LEN + sc8];

    for (int kt0 = 0; kt0 < S_LEN; kt0 += 64) {
        // ---- commit staged regs to LDS ----
        *(uint4*)&Ks[srow * APAD + sc8]  = kreg0;
        *(uint4*)&Ks[srow1 * APAD + sc8] = kreg1;
        *(uint4*)&Vs[srow * APAD + sc8]  = vreg0;
        *(uint4*)&Vs[srow1 * APAD + sc8] = vreg1;
        __syncthreads();

        // ---- prefetch next tile (overlaps with compute below) ----
        int nt = kt0 + 64;
        if (nt < S_LEN) {
            kreg0 = *(const uint4*)&KhG[(long)(nt + srow) * DMODEL + sc8];
            kreg1 = *(const uint4*)&KhG[(long)(nt + srow1) * DMODEL + sc8];
            vreg0 = *(const uint4*)&VtG[(long)srow * S_LEN + nt + sc8];
            vreg1 = *(const uint4*)&VtG[(long)srow1 * S_LEN + nt + sc8];
        }

        // ---- scores transposed: S^T[key][q] = K·Q^T ----
        f32x4 Sa[4];
        #pragma unroll
        for (int m = 0; m < 4; m++) {
            const u16* kp = &Ks[(m * 16 + li) * APAD + g * 8];
            f16x8 k0 = *(const f16x8*)kp, k1 = *(const f16x8*)(kp + 32);
            f32x4 s = (f32x4){0.f, 0.f, 0.f, 0.f};
            s = __builtin_amdgcn_mfma_f32_16x16x32_f16(k0, q0f, s, 0, 0, 0);
            s = __builtin_amdgcn_mfma_f32_16x16x32_f16(k1, q1f, s, 0, 0, 0);
            Sa[m] = s;   // rows: key = m*16 + g*4 + r ; col: query = li
        }

        // ---- bias ----
        const int jb = kt0 + g * 4 + 63 - qloc;
        #pragma unroll
        for (int m = 0; m < 4; m++)
            #pragma unroll
            for (int r = 0; r < 4; r++)
                Sa[m][r] += biasL[jb + m * 16 + r];

        // ---- online softmax: per-lane (one query), 16 keys in regs ----
        float pm = Sa[0][0];
        #pragma unroll
        for (int m = 0; m < 4; m++)
            #pragma unroll
            for (int r = 0; r < 4; r++) pm = fmaxf(pm, Sa[m][r]);
        pm = fmaxf(pm, __shfl_xor(pm, 16));
        pm = fmaxf(pm, __shfl_xor(pm, 32));

        float mn = fmaxf(mP, pm);
        float alpha = __expf(mP - mn);
        mP = mn;
        float aO[4];
        #pragma unroll
        for (int r = 0; r < 4; r++) aO[r] = __shfl(alpha, g * 4 + r);

        float ls = 0.f;
        #pragma unroll
        for (int m = 0; m < 4; m++)
            #pragma unroll
            for (int r = 0; r < 4; r++) {
                Sa[m][r] = __expf(Sa[m][r] - mn);
                ls += Sa[m][r];
            }
        ls += __shfl_xor(ls, 16);
        ls += __shfl_xor(ls, 32);
        lR = lR * alpha + ls;

        // ---- P -> LDS [q][key] via packed cvt; wave-private rows ----
        #pragma unroll
        for (int m = 0; m < 4; m++) {
            u32 lo = pkrtz(Sa[m][0], Sa[m][1]);
            u32 hi = pkrtz(Sa[m][2], Sa[m][3]);
            *(uint2*)&Ps[qloc * APAD + m * 16 + g * 4] = make_uint2(lo, hi);
        }

        // ---- Tc = P · V (independent of Oc), then Oc = Oc*alpha + Tc ----
        f32x4 Tc[4];
        #pragma unroll
        for (int n = 0; n < 4; n++) Tc[n] = (f32x4){0.f, 0.f, 0.f, 0.f};
        {
            const u16* pp = &Ps[qloc * APAD + g * 8];
            f16x8 p0 = *(const f16x8*)pp, p1 = *(const f16x8*)(pp + 32);
            #pragma unroll
            for (int n = 0; n < 4; n++) {
                const u16* vp = &Vs[(n * 16 + li) * APAD + g * 8];
                f16x8 v0 = *(const f16x8*)vp, v1 = *(const f16x8*)(vp + 32);
                Tc[n] = __builtin_amdgcn_mfma_f32_16x16x32_f16(p0, v0, Tc[n], 0, 0, 0);
                Tc[n] = __builtin_amdgcn_mfma_f32_16x16x32_f16(p1, v1, Tc[n], 0, 0, 0);
            }
        }
        #pragma unroll
        for (int n = 0; n < 4; n++)
            #pragma unroll
            for (int r = 0; r < 4; r++)
                Oc[n][r] = fmaf(Oc[n][r], aO[r], Tc[n][r]);

        __syncthreads();   // all waves done with Ks/Vs before next commit
    }

    float linv = 1.0f / lR;
    float iv[4];
    #pragma unroll
    for (int r = 0; r < 4; r++) iv[r] = __shfl(linv, g * 4 + r);
    #pragma unroll
    for (int n = 0; n < 4; n++)
        #pragma unroll
        for (int r = 0; r < 4; r++)
            ctxb[((long)(b * S_LEN + q0 + wv * 16 + g * 4 + r)) * DMODEL
                 + h * DK + n * 16 + li] = f2h(Oc[n][r] * iv[r]);
}

// ------------------------- launcher ----------------------------------------
extern "C" void kernel_launch(void* const* d_in, const int* in_sizes, int n_in,
                              void* d_out, int out_size, void* d_ws, size_t ws_size,
                              hipStream_t stream)
{
    const float* x    = (const float*)d_in[0];
    const float* wq   = (const float*)d_in[1];
    const float* wk   = (const float*)d_in[2];
    const float* wv   = (const float*)d_in[3];
    const float* wo   = (const float*)d_in[4];
    const float* rel  = (const float*)d_in[5];

    u16* W0 = (u16*)d_ws;
    u16* Xf  = W0;                          // fp16 x, row-major (8 MB)
    u16* Qc  = W0 + 4194304;                // fp16 [B*S, 1024]
    u16* Kc  = W0 + 8388608;
    u16* Vc  = W0 + 12582912;               // fp16 [B*S, 1024]
    u16* VT  = W0 + 16777216;               // fp16 [B,H,Dk,S]
    u16* WT  = W0 + 20971520;               // 4 fp16 planes [n][k] (8 MB)
    float* tab = (float*)(W0 + 25165824);   // [16,4096] fp32
    u16* ctxb = Xf;                         // alias: Xf dead after gemm_qkv

    prep_kernel<<<dim3(3328), dim3(256), 0, stream>>>(x, wq, wk, wv, wo, rel,
                                                      Xf, WT, tab);
    gemm_qkv_mfma<<<dim3(8, 32, 3), dim3(256), 0, stream>>>(Xf, WT, Qc, Kc, Vc);
    transpose_v<<<dim3(1024), dim3(256), 0, stream>>>(Vc, VT);
    attn_mfma<<<dim3(1024), dim3(256), 0, stream>>>(Qc, Kc, VT, tab, ctxb);
    gemm_out_mfma<<<dim3(8, 32), dim3(256), 0, stream>>>(ctxb, WT, (float*)d_out);
}

// Round 9
// 357.669 us; speedup vs baseline: 1.0328x; 1.0328x over previous
//
#include <hip/hip_runtime.h>
#include <hip/hip_bf16.h>

typedef __attribute__((ext_vector_type(8))) _Float16 f16x8;
typedef __attribute__((ext_vector_type(2))) __fp16 fp16x2;
typedef __attribute__((ext_vector_type(4))) float f32x4;
typedef unsigned short u16;
typedef unsigned int u32;

#define S_LEN 2048
#define NH    16
#define DK    64
#define DMODEL 1024
#define GSTR  72   // LDS row stride (f16) for BK=64 GEMM staging tiles
#define CS    132  // LDS row stride (f16) for the C-tile epilogue bounce

union F16U { _Float16 h; u16 u; };
__device__ __forceinline__ u16 f2h(float f) {
    F16U v; v.h = (_Float16)f; return v.u;
}
union PKU { fp16x2 h; u32 u; };
__device__ __forceinline__ u32 pkrtz(float a, float b) {
    PKU v; v.h = __builtin_amdgcn_cvt_pkrtz(a, b); return v.u;
}

// ------------------------- fused prep kernel -------------------------------
// blk [0,2048): x -> fp16. blk [2048,3072): W^T fp16 [n][k]. blk [3072,3328): bias table.
__global__ __launch_bounds__(256) void prep_kernel(
    const float* __restrict__ x,
    const float* __restrict__ Wq, const float* __restrict__ Wk,
    const float* __restrict__ Wv, const float* __restrict__ Wo,
    const float* __restrict__ rel_emb,
    u16* __restrict__ Xf, u16* __restrict__ WT, float* __restrict__ tab)
{
    __shared__ __align__(16) float T[64 * 68];
    const int blk = blockIdx.x;
    const int tid = threadIdx.x;

    if (blk < 2048) {
        long i8 = ((long)blk * 256 + tid) * 8;
        float4 a = *(const float4*)&x[i8];
        float4 b = *(const float4*)&x[i8 + 4];
        *(ushort4*)&Xf[i8] =
            make_ushort4(f2h(a.x), f2h(a.y), f2h(a.z), f2h(a.w));
        *(ushort4*)&Xf[i8 + 4] =
            make_ushort4(f2h(b.x), f2h(b.y), f2h(b.z), f2h(b.w));
    } else if (blk < 3072) {
        int id = blk - 2048;
        int z = id >> 8, rem = id & 255;
        int k0 = (rem >> 4) * 64, n0 = (rem & 15) * 64;
        const float* src = (z == 0) ? Wq : (z == 1) ? Wk : (z == 2) ? Wv : Wo;
        u16* dT = WT + (long)z * 1048576;
        #pragma unroll
        for (int u = 0; u < 4; u++) {
            int w = tid + u * 256;
            int r = w >> 4, c4 = (w & 15) * 4;
            *(float4*)&T[r * 68 + c4] =
                *(const float4*)&src[(long)(k0 + r) * DMODEL + n0 + c4];
        }
        __syncthreads();
        #pragma unroll
        for (int u = 0; u < 4; u++) {
            int w = tid + u * 256;
            int n = w >> 4, kc = (w & 15) * 4;
            *(ushort4*)&dT[(long)(n0 + n) * DMODEL + k0 + kc] = make_ushort4(
                f2h(T[(kc + 0) * 68 + n]), f2h(T[(kc + 1) * 68 + n]),
                f2h(T[(kc + 2) * 68 + n]), f2h(T[(kc + 3) * 68 + n]));
        }
    } else {
        // bias table: integer-exact replica of reference fp32 bucket math
        int idx = (blk - 3072) * 256 + tid;   // 0..65535
        int h = idx >> 12;
        int t = idx & 4095;
        int n = -(t - 2048);       // q - k
        int ret = 0;
        if (n < 0) { ret = 16; n = -n; }
        int inner;
        if (n < 8) {
            inner = n;
        } else {
            inner = 8 + (n >= 12) + (n >= 16) + (n >= 23) + (n >= 32)
                      + (n >= 46) + (n >= 64) + (n >= 91);
            if (inner > 15) inner = 15;
        }
        tab[h * 4096 + t] = rel_emb[(ret + inner) * NH + h];
    }
}

// ------------------------- pipelined MFMA GEMM (fp16) ----------------------
// C[4096,1024] = A @ W^T-plane, row-major fp16 out. BK=64, register-prefetch
// staging; epilogue bounces the C tile through LDS for fully-coalesced
// uint4 row stores. __launch_bounds__(256,2): ~256-reg budget, no spills.
__global__ __launch_bounds__(256, 2) void gemm_qkv_mfma(
    const u16* __restrict__ Xf, const u16* __restrict__ WT,
    u16* __restrict__ Qc, u16* __restrict__ Kc, u16* __restrict__ Vc)
{
    const int z = blockIdx.z;
    const u16* BT = WT + (long)z * 1048576;
    u16* O = (z == 0) ? Qc : (z == 1) ? Kc : Vc;

    __shared__ __align__(16) u16 SM[2 * 128 * GSTR];   // staging; reused for C
    u16* Ah = SM;
    u16* Bh = SM + 128 * GSTR;

    const int tid = threadIdx.x;
    const int wv = tid >> 6, lane = tid & 63;
    const int g = lane >> 4, li = lane & 15;
    const int wr = wv >> 1, wc = wv & 1;
    const int bm = blockIdx.y * 128, bn = blockIdx.x * 128;

    const int srow = tid >> 3, sc8 = (tid & 7) * 8;   // staging map

    f32x4 acc[4][4];
    #pragma unroll
    for (int i = 0; i < 4; i++)
        #pragma unroll
        for (int j = 0; j < 4; j++) acc[i][j] = (f32x4){0.f, 0.f, 0.f, 0.f};

    uint4 ra[4], rb[4];
    #pragma unroll
    for (int u = 0; u < 4; u++) {
        ra[u] = *(const uint4*)&Xf[(long)(bm + srow + u * 32) * DMODEL + sc8];
        rb[u] = *(const uint4*)&BT[(long)(bn + srow + u * 32) * DMODEL + sc8];
    }

    for (int k0 = 0; k0 < DMODEL; k0 += 64) {
        #pragma unroll
        for (int u = 0; u < 4; u++) {
            *(uint4*)&Ah[(srow + u * 32) * GSTR + sc8] = ra[u];
            *(uint4*)&Bh[(srow + u * 32) * GSTR + sc8] = rb[u];
        }
        __syncthreads();

        int nk = k0 + 64;
        if (nk < DMODEL) {
            #pragma unroll
            for (int u = 0; u < 4; u++) {
                ra[u] = *(const uint4*)&Xf[(long)(bm + srow + u * 32) * DMODEL + nk + sc8];
                rb[u] = *(const uint4*)&BT[(long)(bn + srow + u * 32) * DMODEL + nk + sc8];
            }
        }

        #pragma unroll
        for (int kk = 0; kk < 2; kk++) {
            f16x8 a_h[4], b_h[4];
            #pragma unroll
            for (int i = 0; i < 4; i++)
                a_h[i] = *(const f16x8*)&Ah[(wr * 64 + i * 16 + li) * GSTR + kk * 32 + g * 8];
            #pragma unroll
            for (int j = 0; j < 4; j++)
                b_h[j] = *(const f16x8*)&Bh[(wc * 64 + j * 16 + li) * GSTR + kk * 32 + g * 8];
            #pragma unroll
            for (int i = 0; i < 4; i++)
                #pragma unroll
                for (int j = 0; j < 4; j++)
                    acc[i][j] = __builtin_amdgcn_mfma_f32_16x16x32_f16(
                        b_h[j], a_h[i], acc[i][j], 0, 0, 0);   // C^T
        }
        __syncthreads();
    }

    // ---- epilogue: C tile -> LDS (stride CS) -> coalesced row stores ----
    #pragma unroll
    for (int i = 0; i < 4; i++) {
        int rl = wr * 64 + i * 16 + li;           // s-row within tile
        #pragma unroll
        for (int j = 0; j < 4; j++) {
            int cl = wc * 64 + j * 16 + g * 4;    // n-col within tile
            *(ushort4*)&SM[rl * CS + cl] = make_ushort4(
                f2h(acc[i][j][0]), f2h(acc[i][j][1]),
                f2h(acc[i][j][2]), f2h(acc[i][j][3]));
        }
    }
    __syncthreads();
    {
        const int rr = tid >> 4, cc = (tid & 15) * 8;
        #pragma unroll
        for (int p = 0; p < 8; p++) {
            int row = p * 16 + rr;
            *(uint4*)&O[(long)(bm + row) * DMODEL + bn + cc] =
                *(const uint4*)&SM[row * CS + cc];
        }
    }
}

// ------------------------- pipelined output GEMM (fp16 -> fp32) ------------
__global__ __launch_bounds__(256, 2) void gemm_out_mfma(
    const u16* __restrict__ Ab, const u16* __restrict__ WT,
    float* __restrict__ O)
{
    const u16* BT = WT + 3L * 1048576;
    __shared__ __align__(16) u16 SM[2 * 128 * GSTR];
    u16* Ah = SM;
    u16* Bh = SM + 128 * GSTR;

    const int tid = threadIdx.x;
    const int wv = tid >> 6, lane = tid & 63;
    const int g = lane >> 4, li = lane & 15;
    const int wr = wv >> 1, wc = wv & 1;
    const int bm = blockIdx.y * 128, bn = blockIdx.x * 128;
    const int srow = tid >> 3, sc8 = (tid & 7) * 8;

    f32x4 acc[4][4];
    #pragma unroll
    for (int i = 0; i < 4; i++)
        #pragma unroll
        for (int j = 0; j < 4; j++) acc[i][j] = (f32x4){0.f, 0.f, 0.f, 0.f};

    uint4 ra[4], rb[4];
    #pragma unroll
    for (int u = 0; u < 4; u++) {
        ra[u] = *(const uint4*)&Ab[(long)(bm + srow + u * 32) * DMODEL + sc8];
        rb[u] = *(const uint4*)&BT[(long)(bn + srow + u * 32) * DMODEL + sc8];
    }

    for (int k0 = 0; k0 < DMODEL; k0 += 64) {
        #pragma unroll
        for (int u = 0; u < 4; u++) {
            *(uint4*)&Ah[(srow + u * 32) * GSTR + sc8] = ra[u];
            *(uint4*)&Bh[(srow + u * 32) * GSTR + sc8] = rb[u];
        }
        __syncthreads();

        int nk = k0 + 64;
        if (nk < DMODEL) {
            #pragma unroll
            for (int u = 0; u < 4; u++) {
                ra[u] = *(const uint4*)&Ab[(long)(bm + srow + u * 32) * DMODEL + nk + sc8];
                rb[u] = *(const uint4*)&BT[(long)(bn + srow + u * 32) * DMODEL + nk + sc8];
            }
        }

        #pragma unroll
        for (int kk = 0; kk < 2; kk++) {
            f16x8 a_h[4], b_h[4];
            #pragma unroll
            for (int i = 0; i < 4; i++)
                a_h[i] = *(const f16x8*)&Ah[(wr * 64 + i * 16 + li) * GSTR + kk * 32 + g * 8];
            #pragma unroll
            for (int j = 0; j < 4; j++)
                b_h[j] = *(const f16x8*)&Bh[(wc * 64 + j * 16 + li) * GSTR + kk * 32 + g * 8];
            #pragma unroll
            for (int i = 0; i < 4; i++)
                #pragma unroll
                for (int j = 0; j < 4; j++)
                    acc[i][j] = __builtin_amdgcn_mfma_f32_16x16x32_f16(
                        b_h[j], a_h[i], acc[i][j], 0, 0, 0);   // C^T
        }
        __syncthreads();
    }

    // direct float4 stores: per row the j-loop fills 512 B contiguous
    #pragma unroll
    for (int i = 0; i < 4; i++) {
        int grow = bm + wr * 64 + i * 16 + li;
        #pragma unroll
        for (int j = 0; j < 4; j++) {
            int gcol = bn + wc * 64 + j * 16 + g * 4;
            *(float4*)&O[(long)grow * DMODEL + gcol] = make_float4(
                acc[i][j][0], acc[i][j][1], acc[i][j][2], acc[i][j][3]);
        }
    }
}

// ------------- V transpose: row-major [B*S, H*64] -> VT [B,H,Dk,S] ---------
__global__ __launch_bounds__(256) void transpose_v(
    const u16* __restrict__ Vc, u16* __restrict__ VT)
{
    __shared__ __align__(16) u16 t[64 * 72];
    const int blk = blockIdx.x;           // 1024 = 32 s-tiles x 32 bh
    const int st = blk & 31, bh = blk >> 5;
    const int b = bh >> 4, h = bh & 15;
    const int s0 = st * 64;
    const u16* src = Vc + ((long)b * S_LEN + s0) * DMODEL + h * DK;
    u16* dst = VT + (long)bh * DK * S_LEN;
    const int tid = threadIdx.x;

    #pragma unroll
    for (int u = 0; u < 2; u++) {
        int w = tid + u * 256;
        int s = w >> 3, c8 = (w & 7) * 8;
        *(uint4*)&t[s * 72 + c8] = *(const uint4*)&src[(long)s * DMODEL + c8];
    }
    __syncthreads();
    #pragma unroll
    for (int u = 0; u < 2; u++) {
        int w = tid + u * 256;
        int d = w >> 3, sc8 = (w & 7) * 8;
        u16 tmp[8];
        #pragma unroll
        for (int j = 0; j < 8; j++) tmp[j] = t[(sc8 + j) * 72 + d];
        *(ushort4*)&dst[(long)d * S_LEN + s0 + sc8]     = make_ushort4(tmp[0], tmp[1], tmp[2], tmp[3]);
        *(ushort4*)&dst[(long)d * S_LEN + s0 + sc8 + 4] = make_ushort4(tmp[4], tmp[5], tmp[6], tmp[7]);
    }
}

// ------------------------- MFMA flash attention (fp16, S^T softmax) --------
// S^T = K·Q^T: each lane owns ONE query (col=li), 16 keys in regs.
// Q/K read from row-major [B*S, H*64]; V^T from [B,H,Dk,S].
#define APAD 72
#define BIAS_LEN 2112

__global__ __launch_bounds__(256, 4) void attn_mfma(
    const u16* __restrict__ Qf, const u16* __restrict__ Kf,
    const u16* __restrict__ VT, const float* __restrict__ tab,
    u16* __restrict__ ctxb)
{
    __shared__ __align__(16) u16 Ks[64 * APAD];
    __shared__ __align__(16) u16 Vs[64 * APAD];    // [dim][key]
    __shared__ __align__(16) u16 Ps[64 * APAD];    // [q][key], wave-private rows
    __shared__ float biasL[BIAS_LEN];

    const int tid = threadIdx.x;
    const int wv = tid >> 6, lane = tid & 63;
    const int g = lane >> 4, li = lane & 15;
    const int qblk = blockIdx.x & 31;
    const int h = (blockIdx.x >> 5) & 15;
    const int b = blockIdx.x >> 9;
    const int q0 = qblk * 64;
    const long bh = b * NH + h;
    const int qloc = wv * 16 + li;     // this lane's query (within block)

    const u16* KhG = Kf + (long)b * S_LEN * DMODEL + h * DK;   // row stride DMODEL
    const u16* VtG = VT + bh * (DK * S_LEN);
    const float* th = tab + h * 4096;

    {
        const float* tb = th + 2048 - q0 - 63;
        for (int j = tid; j < BIAS_LEN; j += 256) biasL[j] = tb[j];
    }

    f16x8 q0f, q1f;
    {
        const u16* ph = Qf + ((long)b * S_LEN + q0 + qloc) * DMODEL + h * DK + g * 8;
        q0f = *(const f16x8*)ph;  q1f = *(const f16x8*)(ph + 32);
    }

    f32x4 Oc[4];
    #pragma unroll
    for (int n = 0; n < 4; n++) Oc[n] = (f32x4){0.f, 0.f, 0.f, 0.f};
    float mP = -1e30f, lR = 0.f;

    // staging register prefetch (2 rows of K and V per thread)
    const int srow = tid >> 3, sc8 = (tid & 7) * 8;        // u=0
    const int srow1 = srow + 32;                           // u=1
    uint4 kreg0, kreg1, vreg0, vreg1;
    kreg0 = *(const uint4*)&KhG[(long)srow * DMODEL + sc8];
    kreg1 = *(const uint4*)&KhG[(long)srow1 * DMODEL + sc8];
    vreg0 = *(const uint4*)&VtG[(long)srow * S_LEN + sc8];
    vreg1 = *(const uint4*)&VtG[(long)srow1 * S_LEN + sc8];

    for (int kt0 = 0; kt0 < S_LEN; kt0 += 64) {
        // ---- commit staged regs to LDS ----
        *(uint4*)&Ks[srow * APAD + sc8]  = kreg0;
        *(uint4*)&Ks[srow1 * APAD + sc8] = kreg1;
        *(uint4*)&Vs[srow * APAD + sc8]  = vreg0;
        *(uint4*)&Vs[srow1 * APAD + sc8] = vreg1;
        __syncthreads();

        // ---- prefetch next tile (overlaps with compute below) ----
        int nt = kt0 + 64;
        if (nt < S_LEN) {
            kreg0 = *(const uint4*)&KhG[(long)(nt + srow) * DMODEL + sc8];
            kreg1 = *(const uint4*)&KhG[(long)(nt + srow1) * DMODEL + sc8];
            vreg0 = *(const uint4*)&VtG[(long)srow * S_LEN + nt + sc8];
            vreg1 = *(const uint4*)&VtG[(long)srow1 * S_LEN + nt + sc8];
        }

        // ---- scores transposed: S^T[key][q] = K·Q^T ----
        f32x4 Sa[4];
        #pragma unroll
        for (int m = 0; m < 4; m++) {
            const u16* kp = &Ks[(m * 16 + li) * APAD + g * 8];
            f16x8 k0 = *(const f16x8*)kp, k1 = *(const f16x8*)(kp + 32);
            f32x4 s = (f32x4){0.f, 0.f, 0.f, 0.f};
            s = __builtin_amdgcn_mfma_f32_16x16x32_f16(k0, q0f, s, 0, 0, 0);
            s = __builtin_amdgcn_mfma_f32_16x16x32_f16(k1, q1f, s, 0, 0, 0);
            Sa[m] = s;   // rows: key = m*16 + g*4 + r ; col: query = li
        }

        // ---- bias ----
        const int jb = kt0 + g * 4 + 63 - qloc;
        #pragma unroll
        for (int m = 0; m < 4; m++)
            #pragma unroll
            for (int r = 0; r < 4; r++)
                Sa[m][r] += biasL[jb + m * 16 + r];

        // ---- online softmax: per-lane (one query), 16 keys in regs ----
        float pm = Sa[0][0];
        #pragma unroll
        for (int m = 0; m < 4; m++)
            #pragma unroll
            for (int r = 0; r < 4; r++) pm = fmaxf(pm, Sa[m][r]);
        pm = fmaxf(pm, __shfl_xor(pm, 16));
        pm = fmaxf(pm, __shfl_xor(pm, 32));

        float mn = fmaxf(mP, pm);
        float alpha = __expf(mP - mn);
        mP = mn;
        float aO[4];
        #pragma unroll
        for (int r = 0; r < 4; r++) aO[r] = __shfl(alpha, g * 4 + r);

        float ls = 0.f;
        #pragma unroll
        for (int m = 0; m < 4; m++)
            #pragma unroll
            for (int r = 0; r < 4; r++) {
                Sa[m][r] = __expf(Sa[m][r] - mn);
                ls += Sa[m][r];
            }
        ls += __shfl_xor(ls, 16);
        ls += __shfl_xor(ls, 32);
        lR = lR * alpha + ls;

        // ---- P -> LDS [q][key] via packed cvt; wave-private rows ----
        #pragma unroll
        for (int m = 0; m < 4; m++) {
            u32 lo = pkrtz(Sa[m][0], Sa[m][1]);
            u32 hi = pkrtz(Sa[m][2], Sa[m][3]);
            *(uint2*)&Ps[qloc * APAD + m * 16 + g * 4] = make_uint2(lo, hi);
        }

        // ---- Tc = P · V (independent of Oc), then Oc = Oc*alpha + Tc ----
        f32x4 Tc[4];
        #pragma unroll
        for (int n = 0; n < 4; n++) Tc[n] = (f32x4){0.f, 0.f, 0.f, 0.f};
        {
            const u16* pp = &Ps[qloc * APAD + g * 8];
            f16x8 p0 = *(const f16x8*)pp, p1 = *(const f16x8*)(pp + 32);
            #pragma unroll
            for (int n = 0; n < 4; n++) {
                const u16* vp = &Vs[(n * 16 + li) * APAD + g * 8];
                f16x8 v0 = *(const f16x8*)vp, v1 = *(const f16x8*)(vp + 32);
                Tc[n] = __builtin_amdgcn_mfma_f32_16x16x32_f16(p0, v0, Tc[n], 0, 0, 0);
                Tc[n] = __builtin_amdgcn_mfma_f32_16x16x32_f16(p1, v1, Tc[n], 0, 0, 0);
            }
        }
        #pragma unroll
        for (int n = 0; n < 4; n++)
            #pragma unroll
            for (int r = 0; r < 4; r++)
                Oc[n][r] = fmaf(Oc[n][r], aO[r], Tc[n][r]);

        __syncthreads();   // all waves done with Ks/Vs before next commit
    }

    float linv = 1.0f / lR;
    float iv[4];
    #pragma unroll
    for (int r = 0; r < 4; r++) iv[r] = __shfl(linv, g * 4 + r);
    #pragma unroll
    for (int n = 0; n < 4; n++)
        #pragma unroll
        for (int r = 0; r < 4; r++)
            ctxb[((long)(b * S_LEN + q0 + wv * 16 + g * 4 + r)) * DMODEL
                 + h * DK + n * 16 + li] = f2h(Oc[n][r] * iv[r]);
}

// ------------------------- launcher ----------------------------------------
extern "C" void kernel_launch(void* const* d_in, const int* in_sizes, int n_in,
                              void* d_out, int out_size, void* d_ws, size_t ws_size,
                              hipStream_t stream)
{
    const float* x    = (const float*)d_in[0];
    const float* wq   = (const float*)d_in[1];
    const float* wk   = (const float*)d_in[2];
    const float* wv   = (const float*)d_in[3];
    const float* wo   = (const float*)d_in[4];
    const float* rel  = (const float*)d_in[5];

    u16* W0 = (u16*)d_ws;
    u16* Xf  = W0;                          // fp16 x, row-major (8 MB)
    u16* Qc  = W0 + 4194304;                // fp16 [B*S, 1024]
    u16* Kc  = W0 + 8388608;
    u16* Vc  = W0 + 12582912;               // fp16 [B*S, 1024]
    u16* VT  = W0 + 16777216;               // fp16 [B,H,Dk,S]
    u16* WT  = W0 + 20971520;               // 4 fp16 planes [n][k] (8 MB)
    float* tab = (float*)(W0 + 25165824);   // [16,4096] fp32
    u16* ctxb = Xf;                         // alias: Xf dead after gemm_qkv

    prep_kernel<<<dim3(3328), dim3(256), 0, stream>>>(x, wq, wk, wv, wo, rel,
                                                      Xf, WT, tab);
    gemm_qkv_mfma<<<dim3(8, 32, 3), dim3(256), 0, stream>>>(Xf, WT, Qc, Kc, Vc);
    transpose_v<<<dim3(1024), dim3(256), 0, stream>>>(Vc, VT);
    attn_mfma<<<dim3(1024), dim3(256), 0, stream>>>(Qc, Kc, VT, tab, ctxb);
    gemm_out_mfma<<<dim3(8, 32), dim3(256), 0, stream>>>(ctxb, WT, (float*)d_out);
}

// Round 10
// 241.625 us; speedup vs baseline: 1.5288x; 1.4803x over previous
//
#include <hip/hip_runtime.h>
#include <hip/hip_bf16.h>

typedef __attribute__((ext_vector_type(8))) _Float16 f16x8;
typedef __attribute__((ext_vector_type(2))) __fp16 fp16x2;
typedef __attribute__((ext_vector_type(4))) float f32x4;
typedef unsigned short u16;
typedef unsigned int u32;

#define S_LEN 2048
#define NH    16
#define DK    64
#define DMODEL 1024
#define LSTR  40   // LDS row stride (f16) for BK=32 GEMM staging
#define CSB   136  // LDS row stride (f16) for C-tile bounce (16B-aligned rows)

union F16U { _Float16 h; u16 u; };
__device__ __forceinline__ u16 f2h(float f) {
    F16U v; v.h = (_Float16)f; return v.u;
}
union PKU { fp16x2 h; u32 u; };
__device__ __forceinline__ u32 pkrtz(float a, float b) {
    PKU v; v.h = __builtin_amdgcn_cvt_pkrtz(a, b); return v.u;
}

// ------------------------- fused prep kernel -------------------------------
__global__ __launch_bounds__(256) void prep_kernel(
    const float* __restrict__ x,
    const float* __restrict__ Wq, const float* __restrict__ Wk,
    const float* __restrict__ Wv, const float* __restrict__ Wo,
    const float* __restrict__ rel_emb,
    u16* __restrict__ Xf, u16* __restrict__ WT, float* __restrict__ tab)
{
    __shared__ __align__(16) float T[64 * 68];
    const int blk = blockIdx.x;
    const int tid = threadIdx.x;

    if (blk < 2048) {
        long i8 = ((long)blk * 256 + tid) * 8;
        float4 a = *(const float4*)&x[i8];
        float4 b = *(const float4*)&x[i8 + 4];
        *(ushort4*)&Xf[i8] =
            make_ushort4(f2h(a.x), f2h(a.y), f2h(a.z), f2h(a.w));
        *(ushort4*)&Xf[i8 + 4] =
            make_ushort4(f2h(b.x), f2h(b.y), f2h(b.z), f2h(b.w));
    } else if (blk < 3072) {
        int id = blk - 2048;
        int z = id >> 8, rem = id & 255;
        int k0 = (rem >> 4) * 64, n0 = (rem & 15) * 64;
        const float* src = (z == 0) ? Wq : (z == 1) ? Wk : (z == 2) ? Wv : Wo;
        u16* dT = WT + (long)z * 1048576;
        #pragma unroll
        for (int u = 0; u < 4; u++) {
            int w = tid + u * 256;
            int r = w >> 4, c4 = (w & 15) * 4;
            *(float4*)&T[r * 68 + c4] =
                *(const float4*)&src[(long)(k0 + r) * DMODEL + n0 + c4];
        }
        __syncthreads();
        #pragma unroll
        for (int u = 0; u < 4; u++) {
            int w = tid + u * 256;
            int n = w >> 4, kc = (w & 15) * 4;
            *(ushort4*)&dT[(long)(n0 + n) * DMODEL + k0 + kc] = make_ushort4(
                f2h(T[(kc + 0) * 68 + n]), f2h(T[(kc + 1) * 68 + n]),
                f2h(T[(kc + 2) * 68 + n]), f2h(T[(kc + 3) * 68 + n]));
        }
    } else {
        // bias table: integer-exact replica of reference fp32 bucket math
        int idx = (blk - 3072) * 256 + tid;   // 0..65535
        int h = idx >> 12;
        int t = idx & 4095;
        int n = -(t - 2048);       // q - k
        int ret = 0;
        if (n < 0) { ret = 16; n = -n; }
        int inner;
        if (n < 8) {
            inner = n;
        } else {
            inner = 8 + (n >= 12) + (n >= 16) + (n >= 23) + (n >= 32)
                      + (n >= 46) + (n >= 64) + (n >= 91);
            if (inner > 15) inner = 15;
        }
        tab[h * 4096 + t] = rel_emb[(ret + inner) * NH + h];
    }
}

// ------------------------- MFMA QKV GEMM (fp16, BK=32, no prefetch) --------
// C[4096,1024] = A @ W^T-plane; C^T accumulation; half-tile LDS bounce
// epilogue -> fully-coalesced 256B row stores into row-major fp16.
__global__ __launch_bounds__(256, 3) void gemm_qkv_mfma(
    const u16* __restrict__ Xf, const u16* __restrict__ WT,
    u16* __restrict__ Qc, u16* __restrict__ Kc, u16* __restrict__ Vc)
{
    const int z = blockIdx.z;
    const u16* BT = WT + (long)z * 1048576;
    u16* O = (z == 0) ? Qc : (z == 1) ? Kc : Vc;

    __shared__ __align__(16) u16 SM[2 * 128 * LSTR];   // staging; reused for C
    u16* Ah = SM;
    u16* Bh = SM + 128 * LSTR;

    const int tid = threadIdx.x;
    const int wv = tid >> 6, lane = tid & 63;
    const int g = lane >> 4, li = lane & 15;
    const int wr = wv >> 1, wc = wv & 1;
    const int bm = blockIdx.y * 128, bn = blockIdx.x * 128;

    f32x4 acc[4][4];
    #pragma unroll
    for (int i = 0; i < 4; i++)
        #pragma unroll
        for (int j = 0; j < 4; j++) acc[i][j] = (f32x4){0.f, 0.f, 0.f, 0.f};

    for (int k0 = 0; k0 < DMODEL; k0 += 32) {
        #pragma unroll
        for (int u = 0; u < 2; u++) {
            int w = tid + u * 256;
            int row = w >> 2, q8 = (w & 3) * 8;
            *(uint4*)&Ah[row * LSTR + q8] =
                *(const uint4*)&Xf[(long)(bm + row) * DMODEL + k0 + q8];
            *(uint4*)&Bh[row * LSTR + q8] =
                *(const uint4*)&BT[(long)(bn + row) * DMODEL + k0 + q8];
        }
        __syncthreads();

        f16x8 a_h[4], b_h[4];
        #pragma unroll
        for (int i = 0; i < 4; i++)
            a_h[i] = *(const f16x8*)&Ah[(wr * 64 + i * 16 + li) * LSTR + g * 8];
        #pragma unroll
        for (int j = 0; j < 4; j++)
            b_h[j] = *(const f16x8*)&Bh[(wc * 64 + j * 16 + li) * LSTR + g * 8];
        #pragma unroll
        for (int i = 0; i < 4; i++)
            #pragma unroll
            for (int j = 0; j < 4; j++)
                acc[i][j] = __builtin_amdgcn_mfma_f32_16x16x32_f16(
                    b_h[j], a_h[i], acc[i][j], 0, 0, 0);   // C^T
        __syncthreads();
    }

    // ---- half-tile bounce epilogue: 64 rows per pass through LDS ----
    #pragma unroll
    for (int h2 = 0; h2 < 2; h2++) {
        if (wr == h2) {
            #pragma unroll
            for (int i = 0; i < 4; i++) {
                int rl = i * 16 + li;                  // row within half-tile
                #pragma unroll
                for (int j = 0; j < 4; j++) {
                    int cl = wc * 64 + j * 16 + g * 4; // col within tile
                    *(ushort4*)&SM[rl * CSB + cl] = make_ushort4(
                        f2h(acc[i][j][0]), f2h(acc[i][j][1]),
                        f2h(acc[i][j][2]), f2h(acc[i][j][3]));
                }
            }
        }
        __syncthreads();
        #pragma unroll
        for (int p = 0; p < 4; p++) {
            int idx = tid + p * 256;
            int row = idx >> 4, c8 = (idx & 15) * 8;
            *(uint4*)&O[(long)(bm + h2 * 64 + row) * DMODEL + bn + c8] =
                *(const uint4*)&SM[row * CSB + c8];
        }
        __syncthreads();
    }
}

// ------------------------- output GEMM (fp16 -> fp32, BK=32) ---------------
__global__ __launch_bounds__(256, 3) void gemm_out_mfma(
    const u16* __restrict__ Ab, const u16* __restrict__ WT,
    float* __restrict__ O)
{
    const u16* BT = WT + 3L * 1048576;
    __shared__ __align__(16) u16 Ah[128 * LSTR], Bh[128 * LSTR];

    const int tid = threadIdx.x;
    const int wv = tid >> 6, lane = tid & 63;
    const int g = lane >> 4, li = lane & 15;
    const int wr = wv >> 1, wc = wv & 1;
    const int bm = blockIdx.y * 128, bn = blockIdx.x * 128;

    f32x4 acc[4][4];
    #pragma unroll
    for (int i = 0; i < 4; i++)
        #pragma unroll
        for (int j = 0; j < 4; j++) acc[i][j] = (f32x4){0.f, 0.f, 0.f, 0.f};

    for (int k0 = 0; k0 < DMODEL; k0 += 32) {
        #pragma unroll
        for (int u = 0; u < 2; u++) {
            int w = tid + u * 256;
            int row = w >> 2, q8 = (w & 3) * 8;
            *(uint4*)&Ah[row * LSTR + q8] =
                *(const uint4*)&Ab[(long)(bm + row) * DMODEL + k0 + q8];
            *(uint4*)&Bh[row * LSTR + q8] =
                *(const uint4*)&BT[(long)(bn + row) * DMODEL + k0 + q8];
        }
        __syncthreads();

        f16x8 a_h[4], b_h[4];
        #pragma unroll
        for (int i = 0; i < 4; i++)
            a_h[i] = *(const f16x8*)&Ah[(wr * 64 + i * 16 + li) * LSTR + g * 8];
        #pragma unroll
        for (int j = 0; j < 4; j++)
            b_h[j] = *(const f16x8*)&Bh[(wc * 64 + j * 16 + li) * LSTR + g * 8];
        #pragma unroll
        for (int i = 0; i < 4; i++)
            #pragma unroll
            for (int j = 0; j < 4; j++)
                acc[i][j] = __builtin_amdgcn_mfma_f32_16x16x32_f16(
                    b_h[j], a_h[i], acc[i][j], 0, 0, 0);   // C^T
        __syncthreads();
    }

    // per row (i): j-loop fills 64 consecutive floats = 256B contiguous
    #pragma unroll
    for (int i = 0; i < 4; i++) {
        int grow = bm + wr * 64 + i * 16 + li;
        #pragma unroll
        for (int j = 0; j < 4; j++) {
            int gcol = bn + wc * 64 + j * 16 + g * 4;
            *(float4*)&O[(long)grow * DMODEL + gcol] = make_float4(
                acc[i][j][0], acc[i][j][1], acc[i][j][2], acc[i][j][3]);
        }
    }
}

// ------------- V transpose: row-major [B*S, H*64] -> VT [B,H,Dk,S] ---------
__global__ __launch_bounds__(256) void transpose_v(
    const u16* __restrict__ Vc, u16* __restrict__ VT)
{
    __shared__ __align__(16) u16 t[64 * 72];
    const int blk = blockIdx.x;           // 1024 = 32 s-tiles x 32 bh
    const int st = blk & 31, bh = blk >> 5;
    const int b = bh >> 4, h = bh & 15;
    const int s0 = st * 64;
    const u16* src = Vc + ((long)b * S_LEN + s0) * DMODEL + h * DK;
    u16* dst = VT + (long)bh * DK * S_LEN;
    const int tid = threadIdx.x;

    #pragma unroll
    for (int u = 0; u < 2; u++) {
        int w = tid + u * 256;
        int s = w >> 3, c8 = (w & 7) * 8;
        *(uint4*)&t[s * 72 + c8] = *(const uint4*)&src[(long)s * DMODEL + c8];
    }
    __syncthreads();
    #pragma unroll
    for (int u = 0; u < 2; u++) {
        int w = tid + u * 256;
        int d = w >> 3, sc8 = (w & 7) * 8;
        u16 tmp[8];
        #pragma unroll
        for (int j = 0; j < 8; j++) tmp[j] = t[(sc8 + j) * 72 + d];
        *(ushort4*)&dst[(long)d * S_LEN + s0 + sc8]     = make_ushort4(tmp[0], tmp[1], tmp[2], tmp[3]);
        *(ushort4*)&dst[(long)d * S_LEN + s0 + sc8 + 4] = make_ushort4(tmp[4], tmp[5], tmp[6], tmp[7]);
    }
}

// ------------------------- MFMA flash attention (fp16, S^T softmax) --------
// S^T = K·Q^T: each lane owns ONE query (col=li), 16 keys in regs.
// No register prefetch (R5-proven staging); bias window hoisted to LDS.
#define APAD 72
#define BIAS_LEN 2112

__global__ __launch_bounds__(256, 4) void attn_mfma(
    const u16* __restrict__ Qf, const u16* __restrict__ Kf,
    const u16* __restrict__ VT, const float* __restrict__ tab,
    u16* __restrict__ ctxb)
{
    __shared__ __align__(16) u16 Ks[64 * APAD];
    __shared__ __align__(16) u16 Vs[64 * APAD];    // [dim][key]
    __shared__ __align__(16) u16 Ps[64 * APAD];    // [q][key], wave-private rows
    __shared__ float biasL[BIAS_LEN];

    const int tid = threadIdx.x;
    const int wv = tid >> 6, lane = tid & 63;
    const int g = lane >> 4, li = lane & 15;
    const int qblk = blockIdx.x & 31;
    const int h = (blockIdx.x >> 5) & 15;
    const int b = blockIdx.x >> 9;
    const int q0 = qblk * 64;
    const long bh = b * NH + h;
    const int qloc = wv * 16 + li;     // this lane's query (within block)

    const u16* KhG = Kf + (long)b * S_LEN * DMODEL + h * DK;   // row stride DMODEL
    const u16* VtG = VT + bh * (DK * S_LEN);
    const float* th = tab + h * 4096;

    {
        const float* tb = th + 2048 - q0 - 63;
        for (int j = tid; j < BIAS_LEN; j += 256) biasL[j] = tb[j];
    }

    f16x8 q0f, q1f;
    {
        const u16* ph = Qf + ((long)b * S_LEN + q0 + qloc) * DMODEL + h * DK + g * 8;
        q0f = *(const f16x8*)ph;  q1f = *(const f16x8*)(ph + 32);
    }

    f32x4 Oc[4];
    #pragma unroll
    for (int n = 0; n < 4; n++) Oc[n] = (f32x4){0.f, 0.f, 0.f, 0.f};
    float mP = -1e30f, lR = 0.f;

    for (int kt0 = 0; kt0 < S_LEN; kt0 += 64) {
        // ---- stage K + V^T tiles ----
        #pragma unroll
        for (int u = 0; u < 2; u++) {
            int w = tid + u * 256;
            int row = w >> 3, c8 = (w & 7) * 8;
            *(uint4*)&Ks[row * APAD + c8] =
                *(const uint4*)&KhG[(long)(kt0 + row) * DMODEL + c8];
            *(uint4*)&Vs[row * APAD + c8] =
                *(const uint4*)&VtG[(long)row * S_LEN + kt0 + c8];
        }
        __syncthreads();

        // ---- scores transposed: S^T[key][q] = K·Q^T ----
        f32x4 Sa[4];
        #pragma unroll
        for (int m = 0; m < 4; m++) {
            const u16* kp = &Ks[(m * 16 + li) * APAD + g * 8];
            f16x8 k0 = *(const f16x8*)kp, k1 = *(const f16x8*)(kp + 32);
            f32x4 s = (f32x4){0.f, 0.f, 0.f, 0.f};
            s = __builtin_amdgcn_mfma_f32_16x16x32_f16(k0, q0f, s, 0, 0, 0);
            s = __builtin_amdgcn_mfma_f32_16x16x32_f16(k1, q1f, s, 0, 0, 0);
            Sa[m] = s;   // rows: key = m*16 + g*4 + r ; col: query = li
        }

        // ---- bias ----
        const int jb = kt0 + g * 4 + 63 - qloc;
        #pragma unroll
        for (int m = 0; m < 4; m++)
            #pragma unroll
            for (int r = 0; r < 4; r++)
                Sa[m][r] += biasL[jb + m * 16 + r];

        // ---- online softmax: per-lane (one query), 16 keys in regs ----
        float pm = Sa[0][0];
        #pragma unroll
        for (int m = 0; m < 4; m++)
            #pragma unroll
            for (int r = 0; r < 4; r++) pm = fmaxf(pm, Sa[m][r]);
        pm = fmaxf(pm, __shfl_xor(pm, 16));
        pm = fmaxf(pm, __shfl_xor(pm, 32));

        float mn = fmaxf(mP, pm);
        float alpha = __expf(mP - mn);
        mP = mn;
        float aO[4];
        #pragma unroll
        for (int r = 0; r < 4; r++) aO[r] = __shfl(alpha, g * 4 + r);

        float ls = 0.f;
        #pragma unroll
        for (int m = 0; m < 4; m++)
            #pragma unroll
            for (int r = 0; r < 4; r++) {
                Sa[m][r] = __expf(Sa[m][r] - mn);
                ls += Sa[m][r];
            }
        ls += __shfl_xor(ls, 16);
        ls += __shfl_xor(ls, 32);
        lR = lR * alpha + ls;

        // ---- P -> LDS [q][key] via packed cvt; wave-private rows ----
        #pragma unroll
        for (int m = 0; m < 4; m++) {
            u32 lo = pkrtz(Sa[m][0], Sa[m][1]);
            u32 hi = pkrtz(Sa[m][2], Sa[m][3]);
            *(uint2*)&Ps[qloc * APAD + m * 16 + g * 4] = make_uint2(lo, hi);
        }

        // ---- Tc = P · V (independent of Oc), then Oc = Oc*alpha + Tc ----
        f32x4 Tc[4];
        #pragma unroll
        for (int n = 0; n < 4; n++) Tc[n] = (f32x4){0.f, 0.f, 0.f, 0.f};
        {
            const u16* pp = &Ps[qloc * APAD + g * 8];
            f16x8 p0 = *(const f16x8*)pp, p1 = *(const f16x8*)(pp + 32);
            #pragma unroll
            for (int n = 0; n < 4; n++) {
                const u16* vp = &Vs[(n * 16 + li) * APAD + g * 8];
                f16x8 v0 = *(const f16x8*)vp, v1 = *(const f16x8*)(vp + 32);
                Tc[n] = __builtin_amdgcn_mfma_f32_16x16x32_f16(p0, v0, Tc[n], 0, 0, 0);
                Tc[n] = __builtin_amdgcn_mfma_f32_16x16x32_f16(p1, v1, Tc[n], 0, 0, 0);
            }
        }
        #pragma unroll
        for (int n = 0; n < 4; n++)
            #pragma unroll
            for (int r = 0; r < 4; r++)
                Oc[n][r] = fmaf(Oc[n][r], aO[r], Tc[n][r]);

        __syncthreads();   // all waves done with Ks/Vs before next staging
    }

    float linv = 1.0f / lR;
    float iv[4];
    #pragma unroll
    for (int r = 0; r < 4; r++) iv[r] = __shfl(linv, g * 4 + r);
    #pragma unroll
    for (int n = 0; n < 4; n++)
        #pragma unroll
        for (int r = 0; r < 4; r++)
            ctxb[((long)(b * S_LEN + q0 + wv * 16 + g * 4 + r)) * DMODEL
                 + h * DK + n * 16 + li] = f2h(Oc[n][r] * iv[r]);
}

// ------------------------- launcher ----------------------------------------
extern "C" void kernel_launch(void* const* d_in, const int* in_sizes, int n_in,
                              void* d_out, int out_size, void* d_ws, size_t ws_size,
                              hipStream_t stream)
{
    const float* x    = (const float*)d_in[0];
    const float* wq   = (const float*)d_in[1];
    const float* wk   = (const float*)d_in[2];
    const float* wv   = (const float*)d_in[3];
    const float* wo   = (const float*)d_in[4];
    const float* rel  = (const float*)d_in[5];

    u16* W0 = (u16*)d_ws;
    u16* Xf  = W0;                          // fp16 x, row-major (8 MB)
    u16* Qc  = W0 + 4194304;                // fp16 [B*S, 1024]
    u16* Kc  = W0 + 8388608;
    u16* Vc  = W0 + 12582912;               // fp16 [B*S, 1024]
    u16* VT  = W0 + 16777216;               // fp16 [B,H,Dk,S]
    u16* WT  = W0 + 20971520;               // 4 fp16 planes [n][k] (8 MB)
    float* tab = (float*)(W0 + 25165824);   // [16,4096] fp32
    u16* ctxb = Xf;                         // alias: Xf dead after gemm_qkv

    prep_kernel<<<dim3(3328), dim3(256), 0, stream>>>(x, wq, wk, wv, wo, rel,
                                                      Xf, WT, tab);
    gemm_qkv_mfma<<<dim3(8, 32, 3), dim3(256), 0, stream>>>(Xf, WT, Qc, Kc, Vc);
    transpose_v<<<dim3(1024), dim3(256), 0, stream>>>(Vc, VT);
    attn_mfma<<<dim3(1024), dim3(256), 0, stream>>>(Qc, Kc, VT, tab, ctxb);
    gemm_out_mfma<<<dim3(8, 32), dim3(256), 0, stream>>>(ctxb, WT, (float*)d_out);
}